// Round 3
// baseline (59.287 us; speedup 1.0000x reference)
//
#include <hip/hip_runtime.h>

#define B_    32
#define T_    256
#define D_    64
#define NSEG_ 32
#define OUTD_ (D_ + (D_*(D_-1))/2)   // 64 + 2016 = 2080

// starts[k] = int(round(1 + k*255/32)) - 1, Python banker's rounding.
// Exact in double; rint() is round-nearest-even -> bit-identical to numpy.
__device__ __forceinline__ int boundary(int k) {
    double v = 1.0 + (double)k * (255.0 / 32.0);
    return (int)rint(v) - 1;
}

// elements of triu(k=1) before row d: d*(127-d)/2
__device__ __forceinline__ int cum(int d) { return (d * (127 - d)) >> 1; }

__global__ __launch_bounds__(256)
void logsig_kernel(const float* __restrict__ inp, float* __restrict__ out) {
    const int s = blockIdx.x;   // segment
    const int b = blockIdx.y;   // batch
    const int t0 = boundary(s);
    const int t1 = boundary(s + 1);
    const int n  = t1 - t0;     // steps (7 or 8); t0+8 <= 255 always

    __shared__ float xs[9][D_];
    // stage 9 rows (always safe), vectorized: 9*16 = 144 float4
    {
        const float4* src4 = (const float4*)(inp + ((size_t)b * T_ + t0) * D_);
        float4* xs4 = (float4*)&xs[0][0];
        int i = threadIdx.x;
        if (i < 144) xs4[i] = src4[i];
    }
    __syncthreads();

    float* o = out + ((size_t)b * NSEG_ + s) * OUTD_;

    const int t = blockIdx.z * 256 + threadIdx.x;   // [0, 1024)
    const int d = t >> 4;

    if (d == 63) {
        // s1 = xb - xa, 16 threads x float4
        const int idx = t - 1008;
        const float4 xa = *(const float4*)&xs[0][idx * 4];
        const float4 xb = *(const float4*)&xs[n][idx * 4];
        float4 r; r.x = xb.x - xa.x; r.y = xb.y - xa.y; r.z = xb.z - xa.z; r.w = xb.w - xa.w;
        *(float4*)&o[idx * 4] = r;
        return;
    }

    const int eb = t & 15;
    if (eb < ((d + 1) >> 2)) return;   // whole 4-block left of diagonal
    const int e0 = eb * 4;

    // load e-columns (float4) and d-column (broadcast)
    float4 xe[9];
    float  xd[9];
    #pragma unroll
    for (int k = 0; k < 9; ++k) {
        xe[k] = *(const float4*)&xs[k][e0];
        xd[k] = xs[k][d];
    }

    // A[d,e] = 0.5*( sum_{k<n} (xd[k]*xe[k+1] - xe[k]*xd[k+1])
    //               - (xd[0]*xe[n] - xe[0]*xd[n]) )
    float ax = 0.f, ay = 0.f, az = 0.f, aw = 0.f;
    #pragma unroll
    for (int k = 0; k < 8; ++k) {
        if (k < n) {
            ax = fmaf(xd[k], xe[k + 1].x, ax); ax = fmaf(-xd[k + 1], xe[k].x, ax);
            ay = fmaf(xd[k], xe[k + 1].y, ay); ay = fmaf(-xd[k + 1], xe[k].y, ay);
            az = fmaf(xd[k], xe[k + 1].z, az); az = fmaf(-xd[k + 1], xe[k].z, az);
            aw = fmaf(xd[k], xe[k + 1].w, aw); aw = fmaf(-xd[k + 1], xe[k].w, aw);
        }
    }
    ax = fmaf(-xd[0], xe[n].x, ax); ax = fmaf(xd[n], xe[0].x, ax);
    ay = fmaf(-xd[0], xe[n].y, ay); ay = fmaf(xd[n], xe[0].y, ay);
    az = fmaf(-xd[0], xe[n].z, az); az = fmaf(xd[n], xe[0].z, az);
    aw = fmaf(-xd[0], xe[n].w, aw); aw = fmaf(xd[n], xe[0].w, aw);

    float* orow = o + D_ + cum(d) - (d + 1);   // + e gives the element
    if (e0 + 0 > d) orow[e0 + 0] = 0.5f * ax;
    if (e0 + 1 > d) orow[e0 + 1] = 0.5f * ay;
    if (e0 + 2 > d) orow[e0 + 2] = 0.5f * az;
    if (e0 + 3 > d) orow[e0 + 3] = 0.5f * aw;
}

extern "C" void kernel_launch(void* const* d_in, const int* in_sizes, int n_in,
                              void* d_out, int out_size, void* d_ws, size_t ws_size,
                              hipStream_t stream) {
    const float* inp = (const float*)d_in[0];
    float* out = (float*)d_out;
    dim3 grid(NSEG_, B_, 4);
    dim3 block(256);
    hipLaunchKernelGGL(logsig_kernel, grid, block, 0, stream, inp, out);
}

// Round 4
// 18.695 us; speedup vs baseline: 3.1712x; 3.1712x over previous
//
#include <hip/hip_runtime.h>

#define B_    32
#define T_    256
#define D_    64
#define NSEG_ 32
#define OUTD_ 2080          // 64 + 2016
#define NCHUNK 520          // OUTD_ / 4 float4 chunks

// starts[k] = int(round(1 + k*255/32)) - 1, Python banker's rounding.
// Exact in double; rint() is round-nearest-even -> bit-identical to numpy.
__device__ __forceinline__ int boundary(int k) {
    double v = 1.0 + (double)k * (255.0 / 32.0);
    return (int)rint(v) - 1;
}

// elements of triu(k=1) before row d: d*(127-d)/2
__device__ __forceinline__ int cum(int d) { return (d * (127 - d)) >> 1; }

// flat triangle index -> row, exact after +-1 correction
__device__ __forceinline__ int row_of(int f) {
    float disc = 16129.0f - 8.0f * (float)f;   // 127^2 - 8f >= 9
    int dd = (int)((127.0f - sqrtf(disc)) * 0.5f);
    dd = max(0, min(62, dd));
    while (dd > 0 && cum(dd) > f) --dd;
    while (cum(dd + 1) <= f) ++dd;
    return dd;
}

__global__ __launch_bounds__(512)
void logsig_kernel(const float* __restrict__ inp, float* __restrict__ out) {
    const int s = blockIdx.x;   // segment
    const int b = blockIdx.y;   // batch
    const int t0 = boundary(s);
    const int t1 = boundary(s + 1);
    const int n  = t1 - t0;     // 7 or 8; t0+8 <= 255 for all s

    __shared__ float xs[9][D_];
    {
        const float4* src4 = (const float4*)(inp + ((size_t)b * T_ + t0) * D_);
        float4* xs4 = (float4*)&xs[0][0];
        int i = threadIdx.x;
        if (i < 144) xs4[i] = src4[i];   // 9 rows x 64 floats
    }
    __syncthreads();

    float4* o4 = (float4*)(out + ((size_t)b * NSEG_ + s) * OUTD_);

    for (int c = threadIdx.x; c < NCHUNK; c += 512) {
        if (c < 16) {
            // s1 = xb - xa
            const float4 xa = *(const float4*)&xs[0][c * 4];
            const float4 xb = *(const float4*)&xs[n][c * 4];
            float4 r; r.x = xb.x - xa.x; r.y = xb.y - xa.y;
            r.z = xb.z - xa.z; r.w = xb.w - xa.w;
            o4[c] = r;
            continue;
        }
        int f = 4 * c - 64;             // flat triangle index of chunk start
        int d = row_of(f);
        int e = d + 1 + (f - cum(d));
        float4 r;

        if (e <= 60) {
            // fast path: all 4 elements in row d
            float xd[9];
            #pragma unroll
            for (int k = 0; k < 9; ++k) xd[k] = xs[k][d];
            float ax = 0.f, ay = 0.f, az = 0.f, aw = 0.f;
            #pragma unroll
            for (int k = 0; k < 8; ++k) {
                if (k < n) {
                    ax = fmaf(xd[k], xs[k+1][e+0], ax); ax = fmaf(-xd[k+1], xs[k][e+0], ax);
                    ay = fmaf(xd[k], xs[k+1][e+1], ay); ay = fmaf(-xd[k+1], xs[k][e+1], ay);
                    az = fmaf(xd[k], xs[k+1][e+2], az); az = fmaf(-xd[k+1], xs[k][e+2], az);
                    aw = fmaf(xd[k], xs[k+1][e+3], aw); aw = fmaf(-xd[k+1], xs[k][e+3], aw);
                }
            }
            ax = fmaf(-xd[0], xs[n][e+0], ax); ax = fmaf(xd[n], xs[0][e+0], ax);
            ay = fmaf(-xd[0], xs[n][e+1], ay); ay = fmaf(xd[n], xs[0][e+1], ay);
            az = fmaf(-xd[0], xs[n][e+2], az); az = fmaf(xd[n], xs[0][e+2], az);
            aw = fmaf(-xd[0], xs[n][e+3], aw); aw = fmaf(xd[n], xs[0][e+3], aw);
            r.x = 0.5f * ax; r.y = 0.5f * ay; r.z = 0.5f * az; r.w = 0.5f * aw;
        } else {
            // general path: chunk may cross row boundary(ies)
            float rr[4];
            #pragma unroll
            for (int i = 0; i < 4; ++i) {
                float acc = 0.f;
                #pragma unroll
                for (int k = 0; k < 8; ++k) {
                    if (k < n) {
                        acc = fmaf(xs[k][d],  xs[k+1][e], acc);
                        acc = fmaf(-xs[k+1][d], xs[k][e], acc);
                    }
                }
                acc = fmaf(-xs[0][d], xs[n][e], acc);
                acc = fmaf( xs[n][d], xs[0][e], acc);
                rr[i] = 0.5f * acc;
                ++e;
                if (e == D_) { ++d; e = d + 1; }   // next row
            }
            r.x = rr[0]; r.y = rr[1]; r.z = rr[2]; r.w = rr[3];
        }
        o4[c] = r;   // lanes consecutive -> full-line coalesced
    }
}

extern "C" void kernel_launch(void* const* d_in, const int* in_sizes, int n_in,
                              void* d_out, int out_size, void* d_ws, size_t ws_size,
                              hipStream_t stream) {
    const float* inp = (const float*)d_in[0];
    float* out = (float*)d_out;
    dim3 grid(NSEG_, B_);
    dim3 block(512);
    hipLaunchKernelGGL(logsig_kernel, grid, block, 0, stream, inp, out);
}

// Round 5
// 18.157 us; speedup vs baseline: 3.2653x; 1.0297x over previous
//
#include <hip/hip_runtime.h>

#define B_    32
#define T_    256
#define D_    64
#define NSEG_ 32
#define OUTD_ 2080          // 64 + 2016
#define NCHUNK 520          // OUTD_ / 4 float4 chunks

typedef float v4f __attribute__((ext_vector_type(4)));

// starts[k] = int(round(1 + k*255/32)) - 1, Python banker's rounding.
// Exact in double; rint() is round-nearest-even -> bit-identical to numpy.
__device__ __forceinline__ int boundary(int k) {
    double v = 1.0 + (double)k * (255.0 / 32.0);
    return (int)rint(v) - 1;
}

// elements of triu(k=1) before row d: d*(127-d)/2
__device__ __forceinline__ int cum(int d) { return (d * (127 - d)) >> 1; }

// flat triangle index -> row, exact after +-1 correction
__device__ __forceinline__ int row_of(int f) {
    float disc = 16129.0f - 8.0f * (float)f;   // 127^2 - 8f >= 9
    int dd = (int)((127.0f - sqrtf(disc)) * 0.5f);
    dd = max(0, min(62, dd));
    while (dd > 0 && cum(dd) > f) --dd;
    while (cum(dd + 1) <= f) ++dd;
    return dd;
}

__global__ __launch_bounds__(512)
void logsig_kernel(const float* __restrict__ inp, float* __restrict__ out) {
    const int s = blockIdx.x;   // segment
    const int b = blockIdx.y;   // batch
    const int t0 = boundary(s);
    const int t1 = boundary(s + 1);
    const int n  = t1 - t0;     // 7 or 8; t0+8 <= 255 for all s

    __shared__ float xs[9][D_];
    {
        const v4f* src4 = (const v4f*)(inp + ((size_t)b * T_ + t0) * D_);
        v4f* xs4 = (v4f*)&xs[0][0];
        int i = threadIdx.x;
        if (i < 144) xs4[i] = __builtin_nontemporal_load(&src4[i]);  // 9 rows x 64 floats
    }
    __syncthreads();

    v4f* o4 = (v4f*)(out + ((size_t)b * NSEG_ + s) * OUTD_);

    for (int c = threadIdx.x; c < NCHUNK; c += 512) {
        if (c < 16) {
            // s1 = xb - xa
            const v4f xa = *(const v4f*)&xs[0][c * 4];
            const v4f xb = *(const v4f*)&xs[n][c * 4];
            v4f r = xb - xa;
            __builtin_nontemporal_store(r, &o4[c]);
            continue;
        }
        int f = 4 * c - 64;             // flat triangle index of chunk start
        int d = row_of(f);
        int e = d + 1 + (f - cum(d));
        v4f r;

        if (e <= 60) {
            // fast path: all 4 elements in row d
            float xd[9];
            #pragma unroll
            for (int k = 0; k < 9; ++k) xd[k] = xs[k][d];
            float ax = 0.f, ay = 0.f, az = 0.f, aw = 0.f;
            #pragma unroll
            for (int k = 0; k < 8; ++k) {
                if (k < n) {
                    ax = fmaf(xd[k], xs[k+1][e+0], ax); ax = fmaf(-xd[k+1], xs[k][e+0], ax);
                    ay = fmaf(xd[k], xs[k+1][e+1], ay); ay = fmaf(-xd[k+1], xs[k][e+1], ay);
                    az = fmaf(xd[k], xs[k+1][e+2], az); az = fmaf(-xd[k+1], xs[k][e+2], az);
                    aw = fmaf(xd[k], xs[k+1][e+3], aw); aw = fmaf(-xd[k+1], xs[k][e+3], aw);
                }
            }
            ax = fmaf(-xd[0], xs[n][e+0], ax); ax = fmaf(xd[n], xs[0][e+0], ax);
            ay = fmaf(-xd[0], xs[n][e+1], ay); ay = fmaf(xd[n], xs[0][e+1], ay);
            az = fmaf(-xd[0], xs[n][e+2], az); az = fmaf(xd[n], xs[0][e+2], az);
            aw = fmaf(-xd[0], xs[n][e+3], aw); aw = fmaf(xd[n], xs[0][e+3], aw);
            r.x = 0.5f * ax; r.y = 0.5f * ay; r.z = 0.5f * az; r.w = 0.5f * aw;
        } else {
            // general path: chunk may cross row boundary(ies)
            float rr[4];
            #pragma unroll
            for (int i = 0; i < 4; ++i) {
                float acc = 0.f;
                #pragma unroll
                for (int k = 0; k < 8; ++k) {
                    if (k < n) {
                        acc = fmaf(xs[k][d],  xs[k+1][e], acc);
                        acc = fmaf(-xs[k+1][d], xs[k][e], acc);
                    }
                }
                acc = fmaf(-xs[0][d], xs[n][e], acc);
                acc = fmaf( xs[n][d], xs[0][e], acc);
                rr[i] = 0.5f * acc;
                ++e;
                if (e == D_) { ++d; e = d + 1; }   // next row
            }
            r.x = rr[0]; r.y = rr[1]; r.z = rr[2]; r.w = rr[3];
        }
        __builtin_nontemporal_store(r, &o4[c]);   // full-line coalesced, L2-bypass stream
    }
}

extern "C" void kernel_launch(void* const* d_in, const int* in_sizes, int n_in,
                              void* d_out, int out_size, void* d_ws, size_t ws_size,
                              hipStream_t stream) {
    const float* inp = (const float*)d_in[0];
    float* out = (float*)d_out;
    dim3 grid(NSEG_, B_);
    dim3 block(512);
    hipLaunchKernelGGL(logsig_kernel, grid, block, 0, stream, inp, out);
}

// Round 6
// 15.976 us; speedup vs baseline: 3.7110x; 1.1365x over previous
//
#include <hip/hip_runtime.h>

#define B_    32
#define T_    256
#define D_    64
#define NSEG_ 32
#define OUTD_ 2080          // 64 + 2016
#define NTRI  2016
#define NCHUNK 520          // OUTD_/4

typedef float v4f __attribute__((ext_vector_type(4)));

// starts[k] = int(round(1 + k*255/32)) - 1, Python banker's rounding.
// Exact in double; rint() (RNE) is bit-identical to numpy.
__device__ __forceinline__ int boundary(int k) {
    double v = 1.0 + (double)k * (255.0 / 32.0);
    return (int)rint(v) - 1;
}
// triu(k=1) elements before row d: d*(127-d)/2
__device__ __forceinline__ int cum(int d) { return (d * (127 - d)) >> 1; }

__global__ __launch_bounds__(256)
void logsig_kernel(const float* __restrict__ inp, float* __restrict__ out) {
    const int s = blockIdx.x;   // segment
    const int b = blockIdx.y;   // batch
    const int t0 = boundary(s);
    const int t1 = boundary(s + 1);
    const int n  = t1 - t0;     // 7 or 8; t0+8 <= 255 for all s

    __shared__ float xs[9][D_];     // 2304 B
    __shared__ float tri[NTRI];     // 8064 B

    // phase 1: stage 9 rows of input (always safe: t0+8 <= 255)
    {
        const v4f* src4 = (const v4f*)(inp + ((size_t)b * T_ + t0) * D_);
        const int i = threadIdx.x;
        if (i < 144) ((v4f*)&xs[0][0])[i] = __builtin_nontemporal_load(&src4[i]);
    }
    __syncthreads();

    // phase 2: 136 upper-tri 4x4 tiles, one per thread
    const int tau = threadIdx.x;
    if (tau < 136) {
        // decode tau -> (ti, tj): row ti has 16-ti tiles (tj = ti..15)
        int r = 0, F = 0;
        while (F + (16 - r) <= tau) { F += 16 - r; ++r; }
        const int ti = r, tj = r + (tau - F);
        const int d0 = ti * 4, e0 = tj * 4;

        v4f xd[9], xe[9];
        #pragma unroll
        for (int k = 0; k < 9; ++k) {
            xd[k] = *(const v4f*)&xs[k][d0];   // ds_read_b128
            xe[k] = *(const v4f*)&xs[k][e0];   // ds_read_b128
        }

        float acc[4][4];
        #pragma unroll
        for (int a = 0; a < 4; ++a)
            #pragma unroll
            for (int bb = 0; bb < 4; ++bb) acc[a][bb] = 0.f;

        // A[d,e] = 0.5*( sum_{k<n} (xd[k]*xe[k+1] - xe[k]*xd[k+1])
        //               - (xd[0]*xe[n] - xe[0]*xd[n]) )
        #pragma unroll
        for (int k = 0; k < 8; ++k) {
            if (k < n) {
                #pragma unroll
                for (int a = 0; a < 4; ++a) {
                    #pragma unroll
                    for (int bb = 0; bb < 4; ++bb) {
                        acc[a][bb] = fmaf(xd[k][a],    xe[k + 1][bb], acc[a][bb]);
                        acc[a][bb] = fmaf(-xd[k + 1][a], xe[k][bb],   acc[a][bb]);
                    }
                }
            }
        }
        #pragma unroll
        for (int a = 0; a < 4; ++a) {
            #pragma unroll
            for (int bb = 0; bb < 4; ++bb) {
                acc[a][bb] = fmaf(-xd[0][a], xe[n][bb], acc[a][bb]);
                acc[a][bb] = fmaf( xd[n][a], xe[0][bb], acc[a][bb]);
            }
        }

        // scatter into LDS triangle buffer
        #pragma unroll
        for (int a = 0; a < 4; ++a) {
            const int d = d0 + a;
            const int base = cum(d) - d - 1;   // + e gives flat index
            #pragma unroll
            for (int bb = 0; bb < 4; ++bb) {
                const int e = e0 + bb;
                if (e > d) tri[base + e] = 0.5f * acc[a][bb];
            }
        }
    }
    __syncthreads();

    // phase 3: stream out, lane-consecutive float4 nt stores
    v4f* o4 = (v4f*)(out + ((size_t)b * NSEG_ + s) * OUTD_);
    for (int c = threadIdx.x; c < NCHUNK; c += 256) {
        v4f r;
        if (c < 16) {
            const v4f xa = *(const v4f*)&xs[0][c * 4];
            const v4f xb = *(const v4f*)&xs[n][c * 4];
            r = xb - xa;
        } else {
            r = *(const v4f*)&tri[4 * c - 64];   // 16B-aligned LDS read
        }
        __builtin_nontemporal_store(r, &o4[c]);
    }
}

extern "C" void kernel_launch(void* const* d_in, const int* in_sizes, int n_in,
                              void* d_out, int out_size, void* d_ws, size_t ws_size,
                              hipStream_t stream) {
    const float* inp = (const float*)d_in[0];
    float* out = (float*)d_out;
    dim3 grid(NSEG_, B_);
    dim3 block(256);
    hipLaunchKernelGGL(logsig_kernel, grid, block, 0, stream, inp, out);
}

// Round 7
// 15.898 us; speedup vs baseline: 3.7293x; 1.0049x over previous
//
#include <hip/hip_runtime.h>

#define B_    32
#define T_    256
#define D_    64
#define NSEG_ 32
#define OUTD_ 2080          // 64 + 2016
#define NTRI  2016
#define NCHUNK 520          // OUTD_/4

typedef float v4f __attribute__((ext_vector_type(4)));

// starts[k] = int(round(1 + k*255/32)) - 1, Python banker's rounding.
// Exact in double; rint() (RNE) is bit-identical to numpy.
__device__ __forceinline__ int boundary(int k) {
    double v = 1.0 + (double)k * (255.0 / 32.0);
    return (int)rint(v) - 1;
}
// triu(k=1) elements before row d: d*(127-d)/2
__device__ __forceinline__ int cum(int d) { return (d * (127 - d)) >> 1; }

__global__ __launch_bounds__(256)
void logsig_kernel(const float* __restrict__ inp, float* __restrict__ out) {
    const int s = blockIdx.x;   // segment
    const int b = blockIdx.y;   // batch
    const int t0 = boundary(s);
    const int t1 = boundary(s + 1);
    const int n  = t1 - t0;     // 7 or 8; t0+8 <= 255 for all s

    __shared__ float xs[9][D_];     // 2304 B
    __shared__ float tri[NTRI];     // 8064 B

    // phase 1: stage 9 rows of input (always safe: t0+8 <= 255)
    {
        const v4f* src4 = (const v4f*)(inp + ((size_t)b * T_ + t0) * D_);
        const int i = threadIdx.x;
        if (i < 144) ((v4f*)&xs[0][0])[i] = src4[i];
    }
    __syncthreads();

    // phase 2: 136 upper-tri 4x4 tiles, one per thread
    const int tau = threadIdx.x;
    if (tau < 136) {
        // decode tau -> (ti, tj): row ti has 16-ti tiles (tj = ti..15)
        int r = 0, F = 0;
        while (F + (16 - r) <= tau) { F += 16 - r; ++r; }
        const int ti = r, tj = r + (tau - F);
        const int d0 = ti * 4, e0 = tj * 4;

        v4f xd[9], xe[9];
        #pragma unroll
        for (int k = 0; k < 9; ++k) {
            xd[k] = *(const v4f*)&xs[k][d0];   // ds_read_b128
            xe[k] = *(const v4f*)&xs[k][e0];   // ds_read_b128
        }

        float acc[4][4];
        #pragma unroll
        for (int a = 0; a < 4; ++a)
            #pragma unroll
            for (int bb = 0; bb < 4; ++bb) acc[a][bb] = 0.f;

        // A[d,e] = 0.5*( sum_{k<n} (xd[k]*xe[k+1] - xe[k]*xd[k+1])
        //               - (xd[0]*xe[n] - xe[0]*xd[n]) )
        #pragma unroll
        for (int k = 0; k < 8; ++k) {
            if (k < n) {
                #pragma unroll
                for (int a = 0; a < 4; ++a) {
                    #pragma unroll
                    for (int bb = 0; bb < 4; ++bb) {
                        acc[a][bb] = fmaf(xd[k][a],    xe[k + 1][bb], acc[a][bb]);
                        acc[a][bb] = fmaf(-xd[k + 1][a], xe[k][bb],   acc[a][bb]);
                    }
                }
            }
        }
        #pragma unroll
        for (int a = 0; a < 4; ++a) {
            #pragma unroll
            for (int bb = 0; bb < 4; ++bb) {
                acc[a][bb] = fmaf(-xd[0][a], xe[n][bb], acc[a][bb]);
                acc[a][bb] = fmaf( xd[n][a], xe[0][bb], acc[a][bb]);
            }
        }

        // scatter into LDS triangle buffer
        #pragma unroll
        for (int a = 0; a < 4; ++a) {
            const int d = d0 + a;
            const int base = cum(d) - d - 1;   // + e gives flat index
            #pragma unroll
            for (int bb = 0; bb < 4; ++bb) {
                const int e = e0 + bb;
                if (e > d) tri[base + e] = 0.5f * acc[a][bb];
            }
        }
    }
    __syncthreads();

    // phase 3: stream out, lane-consecutive float4 stores (L2-merged full lines)
    v4f* o4 = (v4f*)(out + ((size_t)b * NSEG_ + s) * OUTD_);
    for (int c = threadIdx.x; c < NCHUNK; c += 256) {
        v4f r;
        if (c < 16) {
            const v4f xa = *(const v4f*)&xs[0][c * 4];
            const v4f xb = *(const v4f*)&xs[n][c * 4];
            r = xb - xa;
        } else {
            r = *(const v4f*)&tri[4 * c - 64];   // 16B-aligned LDS read
        }
        o4[c] = r;
    }
}

extern "C" void kernel_launch(void* const* d_in, const int* in_sizes, int n_in,
                              void* d_out, int out_size, void* d_ws, size_t ws_size,
                              hipStream_t stream) {
    const float* inp = (const float*)d_in[0];
    float* out = (float*)d_out;
    dim3 grid(NSEG_, B_);
    dim3 block(256);
    hipLaunchKernelGGL(logsig_kernel, grid, block, 0, stream, inp, out);
}